// Round 1
// baseline (1703.179 us; speedup 1.0000x reference)
//
#include <hip/hip_runtime.h>

// Problem constants (SemanticTikTokVQ): N tokens, H embed dim, D code dim, K codes
#define NTOK 32768
#define HDIM 2048
#define DDIM 256
#define KCODE 4096

// ---------------------------------------------------------------------------
// Workspace layout (float offsets)
//   z      : [0,         8388608)   (N*D)   pre-projection output
//   postT  : [8388608,  16777216)   (K*H)   codebook @ post_w.T + post_b
//   z_norm : [16777216, 16809984)   (N)     ||z_n||^2
//   c_norm : [16809984, 16814080)   (K)     ||c_k||^2
//   acc    : [16814080, 16814084)   acc[0]=sum min-dist, acc[1]=sum prior[idx]
//   minpack: [16814088, 16879624)   (N ull) packed (dist_bits<<32 | idx)
//   idx_i  : [16879624, 16912392)   (N int) winning indices
// Total ~67.6 MB
// ---------------------------------------------------------------------------

__global__ void cnorm_kernel(const float* __restrict__ codebook, float* __restrict__ c_norm) {
    int k = blockIdx.x;
    int lane = threadIdx.x;  // 64 threads
    float4 v = *(const float4*)(codebook + (size_t)k * DDIM + lane * 4);
    float s = v.x * v.x + v.y * v.y + v.z * v.z + v.w * v.w;
#pragma unroll
    for (int m = 32; m; m >>= 1) s += __shfl_down(s, m, 64);
    if (lane == 0) c_norm[k] = s;
}

// z = embed @ pre_w.T + pre_b  (M=N=32768, K=H=2048, N=D=256), also z_norm via atomics
__global__ __launch_bounds__(256) void gemm_pre_kernel(
    const float* __restrict__ embed, const float* __restrict__ pre_w,
    const float* __restrict__ pre_b, float* __restrict__ z, float* __restrict__ z_norm) {
    __shared__ __align__(16) float As[16][132];
    __shared__ __align__(16) float Bs[16][132];
    const int tid = threadIdx.x;
    const int tx = tid & 15, ty = tid >> 4;
    const int r0 = blockIdx.x * 128;   // token rows
    const int d0 = blockIdx.y * 128;   // output cols (D)

    float acc[8][8];
#pragma unroll
    for (int i = 0; i < 8; ++i)
#pragma unroll
        for (int j = 0; j < 8; ++j) acc[i][j] = 0.f;

    for (int kt = 0; kt < HDIM; kt += 16) {
#pragma unroll
        for (int j = 0; j < 2; ++j) {
            int s = tid + j * 256;
            int row = s >> 2, c4 = (s & 3) * 4;
            float4 v = *(const float4*)(embed + (size_t)(r0 + row) * HDIM + kt + c4);
            As[c4 + 0][row] = v.x; As[c4 + 1][row] = v.y; As[c4 + 2][row] = v.z; As[c4 + 3][row] = v.w;
            float4 w = *(const float4*)(pre_w + (size_t)(d0 + row) * HDIM + kt + c4);
            Bs[c4 + 0][row] = w.x; Bs[c4 + 1][row] = w.y; Bs[c4 + 2][row] = w.z; Bs[c4 + 3][row] = w.w;
        }
        __syncthreads();
#pragma unroll
        for (int kk = 0; kk < 16; ++kk) {
            float4 a0 = *(const float4*)&As[kk][ty * 4];
            float4 a1 = *(const float4*)&As[kk][64 + ty * 4];
            float4 b0 = *(const float4*)&Bs[kk][tx * 4];
            float4 b1 = *(const float4*)&Bs[kk][64 + tx * 4];
            float a[8] = {a0.x, a0.y, a0.z, a0.w, a1.x, a1.y, a1.z, a1.w};
            float b[8] = {b0.x, b0.y, b0.z, b0.w, b1.x, b1.y, b1.z, b1.w};
#pragma unroll
            for (int i = 0; i < 8; ++i)
#pragma unroll
                for (int j = 0; j < 8; ++j) acc[i][j] = fmaf(a[i], b[j], acc[i][j]);
        }
        __syncthreads();
    }

    float4 pb0 = *(const float4*)(pre_b + d0 + tx * 4);
    float4 pb1 = *(const float4*)(pre_b + d0 + 64 + tx * 4);
#pragma unroll
    for (int i = 0; i < 8; ++i) {
        int rr = (i < 4) ? (ty * 4 + i) : (64 + ty * 4 + (i - 4));
        int r = r0 + rr;
        float4 v0 = make_float4(acc[i][0] + pb0.x, acc[i][1] + pb0.y, acc[i][2] + pb0.z, acc[i][3] + pb0.w);
        float4 v1 = make_float4(acc[i][4] + pb1.x, acc[i][5] + pb1.y, acc[i][6] + pb1.z, acc[i][7] + pb1.w);
        *(float4*)(z + (size_t)r * DDIM + d0 + tx * 4) = v0;
        *(float4*)(z + (size_t)r * DDIM + d0 + 64 + tx * 4) = v1;
        float s = v0.x * v0.x + v0.y * v0.y + v0.z * v0.z + v0.w * v0.w +
                  v1.x * v1.x + v1.y * v1.y + v1.z * v1.z + v1.w * v1.w;
#pragma unroll
        for (int m = 1; m <= 8; m <<= 1) s += __shfl_xor(s, m, 64);
        if (tx == 0) atomicAdd(&z_norm[r], s);
    }
}

// Fused distance + argmin: d[n,k] = (||z||^2 + ||c||^2) - 2*z.c, running min per row,
// packed atomicMin across blocks. Tie-break = lowest k, matching np.argmin.
__global__ __launch_bounds__(256) void dist_argmin_kernel(
    const float* __restrict__ z, const float* __restrict__ codebook,
    const float* __restrict__ c_norm, const float* __restrict__ z_norm,
    unsigned long long* __restrict__ minpack) {
    __shared__ __align__(16) float As[16][132];
    __shared__ __align__(16) float Bs[16][132];
    const int tid = threadIdx.x;
    const int tx = tid & 15, ty = tid >> 4;
    const int r0 = blockIdx.x * 128;
    const int kbase = blockIdx.y * (KCODE / 2);

    float zn[8];
#pragma unroll
    for (int i = 0; i < 8; ++i) {
        int rr = (i < 4) ? (ty * 4 + i) : (64 + ty * 4 + (i - 4));
        zn[i] = z_norm[r0 + rr];
    }

    float mval[8];
    int midx[8];
#pragma unroll
    for (int i = 0; i < 8; ++i) { mval[i] = 3.4e38f; midx[i] = 0; }

    for (int kc = 0; kc < KCODE / 2; kc += 128) {
        const int k0 = kbase + kc;
        float acc[8][8];
#pragma unroll
        for (int i = 0; i < 8; ++i)
#pragma unroll
            for (int j = 0; j < 8; ++j) acc[i][j] = 0.f;

        for (int dt = 0; dt < DDIM; dt += 16) {
#pragma unroll
            for (int j = 0; j < 2; ++j) {
                int s = tid + j * 256;
                int row = s >> 2, c4 = (s & 3) * 4;
                float4 v = *(const float4*)(z + (size_t)(r0 + row) * DDIM + dt + c4);
                As[c4 + 0][row] = v.x; As[c4 + 1][row] = v.y; As[c4 + 2][row] = v.z; As[c4 + 3][row] = v.w;
                float4 w = *(const float4*)(codebook + (size_t)(k0 + row) * DDIM + dt + c4);
                Bs[c4 + 0][row] = w.x; Bs[c4 + 1][row] = w.y; Bs[c4 + 2][row] = w.z; Bs[c4 + 3][row] = w.w;
            }
            __syncthreads();
#pragma unroll
            for (int kk = 0; kk < 16; ++kk) {
                float4 a0 = *(const float4*)&As[kk][ty * 4];
                float4 a1 = *(const float4*)&As[kk][64 + ty * 4];
                float4 b0 = *(const float4*)&Bs[kk][tx * 4];
                float4 b1 = *(const float4*)&Bs[kk][64 + tx * 4];
                float a[8] = {a0.x, a0.y, a0.z, a0.w, a1.x, a1.y, a1.z, a1.w};
                float b[8] = {b0.x, b0.y, b0.z, b0.w, b1.x, b1.y, b1.z, b1.w};
#pragma unroll
                for (int i = 0; i < 8; ++i)
#pragma unroll
                    for (int j = 0; j < 8; ++j) acc[i][j] = fmaf(a[i], b[j], acc[i][j]);
            }
            __syncthreads();
        }

        float4 cn0 = *(const float4*)(c_norm + k0 + tx * 4);
        float4 cn1 = *(const float4*)(c_norm + k0 + 64 + tx * 4);
        float cn[8] = {cn0.x, cn0.y, cn0.z, cn0.w, cn1.x, cn1.y, cn1.z, cn1.w};
#pragma unroll
        for (int i = 0; i < 8; ++i) {
#pragma unroll
            for (int j = 0; j < 8; ++j) {
                // match np rounding: t = (z2 + c2); d = t - 2*dot  (2*dot exact, one rounding)
                float t = zn[i] + cn[j];
                float d = fmaf(-2.f, acc[i][j], t);
                int k = k0 + ((j < 4) ? (tx * 4 + j) : (64 + tx * 4 + (j - 4)));
                if (d < mval[i]) { mval[i] = d; midx[i] = k; }  // strict <: first (lowest k) wins
            }
        }
    }

#pragma unroll
    for (int i = 0; i < 8; ++i) {
        int rr = (i < 4) ? (ty * 4 + i) : (64 + ty * 4 + (i - 4));
        int r = r0 + rr;
        unsigned long long p =
            (((unsigned long long)__float_as_uint(mval[i])) << 32) | (unsigned)midx[i];
#pragma unroll
        for (int m = 1; m <= 8; m <<= 1) {
            unsigned long long q = __shfl_xor(p, m, 64);
            if (q < p) p = q;
        }
        if (tx == 0) atomicMin(&minpack[r], p);
    }
}

__global__ void unpack_kernel(const unsigned long long* __restrict__ minpack,
                              const float* __restrict__ prior, int* __restrict__ idx_i,
                              float* __restrict__ out_idx, int idx64,
                              float* __restrict__ accum) {
    int n = blockIdx.x * 256 + threadIdx.x;
    unsigned long long p = minpack[n];
    int k = (int)(p & 0xffffffffull);
    float dist = __uint_as_float((unsigned)(p >> 32));
    idx_i[n] = k;
    if (idx64) ((long long*)out_idx)[n] = (long long)k;
    else out_idx[n] = (float)k;
    float sd = dist;
    float sp = prior[k];
#pragma unroll
    for (int m = 32; m; m >>= 1) {
        sd += __shfl_down(sd, m, 64);
        sp += __shfl_down(sp, m, 64);
    }
    __shared__ float ld[8];
    int lane = threadIdx.x & 63, wid = threadIdx.x >> 6;
    if (lane == 0) { ld[wid] = sd; ld[4 + wid] = sp; }
    __syncthreads();
    if (threadIdx.x == 0) {
        atomicAdd(&accum[0], ld[0] + ld[1] + ld[2] + ld[3]);
        atomicAdd(&accum[1], ld[4] + ld[5] + ld[6] + ld[7]);
    }
}

__global__ void finalize_kernel(const float* __restrict__ prior, const float* __restrict__ accum,
                                float* __restrict__ out_scalars) {
    __shared__ float wred[4];
    __shared__ float wred2[4];
    int tid = threadIdx.x;
    int lane = tid & 63, wid = tid >> 6;
    float mx = -3.4e38f;
    for (int i = tid; i < KCODE; i += 256) mx = fmaxf(mx, prior[i]);
#pragma unroll
    for (int m = 32; m; m >>= 1) mx = fmaxf(mx, __shfl_down(mx, m, 64));
    if (lane == 0) wred[wid] = mx;
    __syncthreads();
    mx = fmaxf(fmaxf(wred[0], wred[1]), fmaxf(wred[2], wred[3]));
    float se = 0.f;
    for (int i = tid; i < KCODE; i += 256) se += expf(prior[i] - mx);
#pragma unroll
    for (int m = 32; m; m >>= 1) se += __shfl_down(se, m, 64);
    if (lane == 0) wred2[wid] = se;
    __syncthreads();
    if (tid == 0) {
        float logZ = mx + logf(wred2[0] + wred2[1] + wred2[2] + wred2[3]);
        float rate = ((float)NTOK * logZ - accum[1]) * 1.4426950408889634f;  // /ln2
        float vq = 1.25f * accum[0] / ((float)NTOK * (float)DDIM);
        out_scalars[0] = rate;
        out_scalars[1] = vq;
    }
}

// postT = codebook @ post_w.T + post_b  (M=K=4096, K=D=256, N=H=2048)
__global__ __launch_bounds__(256) void gemm_post_kernel(
    const float* __restrict__ codebook, const float* __restrict__ post_w,
    const float* __restrict__ post_b, float* __restrict__ postT) {
    __shared__ __align__(16) float As[16][132];
    __shared__ __align__(16) float Bs[16][132];
    const int tid = threadIdx.x;
    const int tx = tid & 15, ty = tid >> 4;
    const int k0 = blockIdx.x * 128;  // code rows
    const int h0 = blockIdx.y * 128;  // output cols (H)

    float acc[8][8];
#pragma unroll
    for (int i = 0; i < 8; ++i)
#pragma unroll
        for (int j = 0; j < 8; ++j) acc[i][j] = 0.f;

    for (int dt = 0; dt < DDIM; dt += 16) {
#pragma unroll
        for (int j = 0; j < 2; ++j) {
            int s = tid + j * 256;
            int row = s >> 2, c4 = (s & 3) * 4;
            float4 v = *(const float4*)(codebook + (size_t)(k0 + row) * DDIM + dt + c4);
            As[c4 + 0][row] = v.x; As[c4 + 1][row] = v.y; As[c4 + 2][row] = v.z; As[c4 + 3][row] = v.w;
            float4 w = *(const float4*)(post_w + (size_t)(h0 + row) * DDIM + dt + c4);
            Bs[c4 + 0][row] = w.x; Bs[c4 + 1][row] = w.y; Bs[c4 + 2][row] = w.z; Bs[c4 + 3][row] = w.w;
        }
        __syncthreads();
#pragma unroll
        for (int kk = 0; kk < 16; ++kk) {
            float4 a0 = *(const float4*)&As[kk][ty * 4];
            float4 a1 = *(const float4*)&As[kk][64 + ty * 4];
            float4 b0 = *(const float4*)&Bs[kk][tx * 4];
            float4 b1 = *(const float4*)&Bs[kk][64 + tx * 4];
            float a[8] = {a0.x, a0.y, a0.z, a0.w, a1.x, a1.y, a1.z, a1.w};
            float b[8] = {b0.x, b0.y, b0.z, b0.w, b1.x, b1.y, b1.z, b1.w};
#pragma unroll
            for (int i = 0; i < 8; ++i)
#pragma unroll
                for (int j = 0; j < 8; ++j) acc[i][j] = fmaf(a[i], b[j], acc[i][j]);
        }
        __syncthreads();
    }

    float4 pb0 = *(const float4*)(post_b + h0 + tx * 4);
    float4 pb1 = *(const float4*)(post_b + h0 + 64 + tx * 4);
#pragma unroll
    for (int i = 0; i < 8; ++i) {
        int rr = (i < 4) ? (ty * 4 + i) : (64 + ty * 4 + (i - 4));
        int k = k0 + rr;
        float4 v0 = make_float4(acc[i][0] + pb0.x, acc[i][1] + pb0.y, acc[i][2] + pb0.z, acc[i][3] + pb0.w);
        float4 v1 = make_float4(acc[i][4] + pb1.x, acc[i][5] + pb1.y, acc[i][6] + pb1.z, acc[i][7] + pb1.w);
        *(float4*)(postT + (size_t)k * HDIM + h0 + tx * 4) = v0;
        *(float4*)(postT + (size_t)k * HDIM + h0 + 64 + tx * 4) = v1;
    }
}

__global__ void gather_kernel(const float* __restrict__ postT, const int* __restrict__ idx_i,
                              float* __restrict__ out) {
    int n = blockIdx.x;
    int k = idx_i[n];
    const float4* src = (const float4*)(postT + (size_t)k * HDIM);
    float4* dst = (float4*)(out + (size_t)n * HDIM);
    int t = threadIdx.x;
    dst[t] = src[t];
    dst[t + 256] = src[t + 256];
}

extern "C" void kernel_launch(void* const* d_in, const int* in_sizes, int n_in,
                              void* d_out, int out_size, void* d_ws, size_t ws_size,
                              hipStream_t stream) {
    const float* embed = (const float*)d_in[0];
    const float* pre_w = (const float*)d_in[1];
    const float* pre_b = (const float*)d_in[2];
    const float* codebook = (const float*)d_in[3];
    const float* post_w = (const float*)d_in[4];
    const float* post_b = (const float*)d_in[5];
    const float* prior = (const float*)d_in[6];
    float* out = (float*)d_out;

    float* ws = (float*)d_ws;
    float* z = ws;
    float* postT = ws + 8388608;
    float* z_norm = ws + 16777216;
    float* c_norm = ws + 16809984;
    float* accum = ws + 16814080;
    unsigned long long* minpack = (unsigned long long*)(ws + 16814088);
    int* idx_i = (int*)(ws + 16879624);

    if (ws_size < (size_t)16912392 * 4) return;  // workspace too small; fail visibly

    hipMemsetAsync(z_norm, 0, NTOK * 4, stream);
    hipMemsetAsync(accum, 0, 16, stream);
    hipMemsetAsync(minpack, 0xFF, NTOK * 8, stream);

    cnorm_kernel<<<KCODE, 64, 0, stream>>>(codebook, c_norm);
    gemm_pre_kernel<<<dim3(NTOK / 128, 2), 256, 0, stream>>>(embed, pre_w, pre_b, z, z_norm);
    dist_argmin_kernel<<<dim3(NTOK / 128, 2), 256, 0, stream>>>(z, codebook, c_norm, z_norm, minpack);

    // indices may be stored as 1 float slot each, or 2 slots (int64) — detect from out_size
    int idx64 = (out_size == NTOK * HDIM + 2 * NTOK + 2) ? 1 : 0;
    unpack_kernel<<<NTOK / 256, 256, 0, stream>>>(minpack, prior, idx_i,
                                                  out + (size_t)NTOK * HDIM, idx64, accum);
    finalize_kernel<<<1, 256, 0, stream>>>(prior, accum, out + (out_size - 2));
    gemm_post_kernel<<<dim3(KCODE / 128, HDIM / 128), 256, 0, stream>>>(codebook, post_w, post_b, postT);
    gather_kernel<<<NTOK, 256, 0, stream>>>(postT, idx_i, out);
}

// Round 2
// 906.858 us; speedup vs baseline: 1.8781x; 1.8781x over previous
//
#include <hip/hip_runtime.h>

#define NTOK 32768
#define HDIM 2048
#define DDIM 256
#define KCODE 4096

typedef _Float16 half8 __attribute__((ext_vector_type(8)));
typedef _Float16 half4 __attribute__((ext_vector_type(4)));
typedef float floatx4 __attribute__((ext_vector_type(4)));
typedef unsigned int u32;
typedef unsigned long long u64;

// async 16B global->LDS copy. LDS dest must be wave-uniform base + lane*16:
// we always assign thread t the LDS slot t*16 (+ wave-uniform strides), which satisfies it.
__device__ __forceinline__ void gload16(const void* g, void* l) {
    __builtin_amdgcn_global_load_lds((const __attribute__((address_space(1))) u32*)g,
                                     (__attribute__((address_space(3))) u32*)l, 16, 0, 0);
}

// ---------------------------------------------------------------------------
// Workspace (float offsets). postT aliases z_hi/z_lo: z splits are dead after
// dist_mfma, and gemm_post is stream-ordered after it.
//   Z_HI    0         (4194304)   N*D f16
//   Z_LO    4194304   (4194304)
//   POSTT   0         (8388608)   K*H f32  [alias]
//   C_HI    8388608   (524288)    K*D f16
//   C_LO    8912896   (524288)
//   PW_HI   9437184   (262144)    D*H f16
//   PW_LO   9699328   (262144)
//   Z_NORM  9961472   (32768)
//   C_NORM  9994240   (4096)
//   ACCUM   9998336   (4)
//   MINPACK 9998340   (65536)     N u64 (byte off %8==0)
//   IDX     10063876  (32768)
//   END     10096644  -> 40.4 MB
// ---------------------------------------------------------------------------
#define WS_Z_HI 0
#define WS_Z_LO 4194304
#define WS_POSTT 0
#define WS_C_HI 8388608
#define WS_C_LO 8912896
#define WS_PW_HI 9437184
#define WS_PW_LO 9699328
#define WS_Z_NORM 9961472
#define WS_C_NORM 9994240
#define WS_ACCUM 9998336
#define WS_MINPACK 9998340
#define WS_IDX 10063876
#define WS_END 10096644

// split pre_w (256x2048 f32) into f16 hi/lo
__global__ void split_pw_kernel(const float* __restrict__ pw, _Float16* __restrict__ h,
                                _Float16* __restrict__ l) {
    int idx = blockIdx.x * 256 + threadIdx.x;  // 131072 float4s
    float4 v = *(const float4*)(pw + (size_t)idx * 4);
    float vv[4] = {v.x, v.y, v.z, v.w};
    half4 hh, ll;
#pragma unroll
    for (int e = 0; e < 4; ++e) {
        _Float16 a = (_Float16)vv[e];
        hh[e] = a;
        ll[e] = (_Float16)(vv[e] - (float)a);
    }
    *(half4*)(h + (size_t)idx * 4) = hh;
    *(half4*)(l + (size_t)idx * 4) = ll;
}

// split codebook (4096x256) into f16 hi/lo + row norms (f32)
__global__ void split_cb_kernel(const float* __restrict__ cb, _Float16* __restrict__ ch,
                                _Float16* __restrict__ cl, float* __restrict__ c_norm) {
    int k = blockIdx.x;
    int lane = threadIdx.x;  // 64
    float4 v = *(const float4*)(cb + (size_t)k * DDIM + lane * 4);
    float vv[4] = {v.x, v.y, v.z, v.w};
    half4 hh, ll;
    float s = 0.f;
#pragma unroll
    for (int e = 0; e < 4; ++e) {
        _Float16 a = (_Float16)vv[e];
        hh[e] = a;
        ll[e] = (_Float16)(vv[e] - (float)a);
        s += vv[e] * vv[e];
    }
    *(half4*)(ch + (size_t)k * DDIM + lane * 4) = hh;
    *(half4*)(cl + (size_t)k * DDIM + lane * 4) = ll;
#pragma unroll
    for (int m = 32; m; m >>= 1) s += __shfl_down(s, m, 64);
    if (lane == 0) c_norm[k] = s;
}

// ---------------------------------------------------------------------------
// pre-GEMM (MFMA split-f16): z = embed @ pre_w.T + pre_b
// M=32768, K=2048, N=256. Block 128x128, BK=64, 4 waves (each 64x64).
// A (embed) staged f32->reg->split->LDS; B (pre_w splits) via global_load_lds.
// Emits z_hi/z_lo (f16) + z_norm. XOR-swizzled LDS chunks (16B granule).
// ---------------------------------------------------------------------------
__global__ __launch_bounds__(256) void pre_mfma_kernel(
    const float* __restrict__ embed, const _Float16* __restrict__ pwh,
    const _Float16* __restrict__ pwl, const float* __restrict__ pre_b,
    _Float16* __restrict__ zh, _Float16* __restrict__ zl, float* __restrict__ z_norm) {
    __shared__ _Float16 Ah[8192], Al[8192], Bh[8192], Bl[8192];
    const int tid = threadIdx.x;
    const int w = tid >> 6, l = tid & 63;
    const int wy = (w >> 1) * 64, wx = (w & 1) * 64;
    const int m0 = blockIdx.y * 128, n0 = blockIdx.x * 128;
    const int lr = l & 15, quad = l >> 4;

    floatx4 acc[4][4] = {};

    for (int kt = 0; kt < HDIM; kt += 64) {
        __syncthreads();
#pragma unroll
        for (int j = 0; j < 4; ++j) {
            int s = j * 256 + tid;
            int row = s >> 3, c = s & 7, gc = c ^ (row & 7);
            gload16(pwh + (size_t)(n0 + row) * HDIM + kt + gc * 8, Bh + s * 8);
            gload16(pwl + (size_t)(n0 + row) * HDIM + kt + gc * 8, Bl + s * 8);
        }
#pragma unroll
        for (int j = 0; j < 4; ++j) {
            int s = j * 256 + tid;
            int row = s >> 3, c = s & 7, gc = c ^ (row & 7);
            const float* gp = embed + (size_t)(m0 + row) * HDIM + kt + gc * 8;
            float4 v0 = *(const float4*)gp;
            float4 v1 = *(const float4*)(gp + 4);
            float vv[8] = {v0.x, v0.y, v0.z, v0.w, v1.x, v1.y, v1.z, v1.w};
            half8 hh, ll;
#pragma unroll
            for (int e = 0; e < 8; ++e) {
                _Float16 a = (_Float16)vv[e];
                hh[e] = a;
                ll[e] = (_Float16)(vv[e] - (float)a);
            }
            *(half8*)(Ah + s * 8) = hh;
            *(half8*)(Al + s * 8) = ll;
        }
        __builtin_amdgcn_s_waitcnt(0);
        __syncthreads();
#pragma unroll
        for (int ks = 0; ks < 2; ++ks) {
            int c = ks * 4 + quad;
            half8 ah[4], al[4], bh[4], bl[4];
#pragma unroll
            for (int i = 0; i < 4; ++i) {
                int ar = wy + 16 * i + lr;
                int as = ar * 8 + (c ^ (ar & 7));
                ah[i] = *(const half8*)(Ah + as * 8);
                al[i] = *(const half8*)(Al + as * 8);
                int br = wx + 16 * i + lr;
                int bs = br * 8 + (c ^ (br & 7));
                bh[i] = *(const half8*)(Bh + bs * 8);
                bl[i] = *(const half8*)(Bl + bs * 8);
            }
#pragma unroll
            for (int i = 0; i < 4; ++i)
#pragma unroll
                for (int j = 0; j < 4; ++j) {
                    acc[i][j] = __builtin_amdgcn_mfma_f32_16x16x32_f16(ah[i], bh[j], acc[i][j], 0, 0, 0);
                    acc[i][j] = __builtin_amdgcn_mfma_f32_16x16x32_f16(ah[i], bl[j], acc[i][j], 0, 0, 0);
                    acc[i][j] = __builtin_amdgcn_mfma_f32_16x16x32_f16(al[i], bh[j], acc[i][j], 0, 0, 0);
                }
        }
    }

    float bias[4];
#pragma unroll
    for (int j = 0; j < 4; ++j) bias[j] = pre_b[n0 + wx + 16 * j + lr];
#pragma unroll
    for (int i = 0; i < 4; ++i) {
#pragma unroll
        for (int r = 0; r < 4; ++r) {
            int m = m0 + wy + 16 * i + quad * 4 + r;
            float s2 = 0.f;
#pragma unroll
            for (int j = 0; j < 4; ++j) {
                float v = acc[i][j][r] + bias[j];
                int n = n0 + wx + 16 * j + lr;
                _Float16 a = (_Float16)v;
                zh[(size_t)m * DDIM + n] = a;
                zl[(size_t)m * DDIM + n] = (_Float16)(v - (float)a);
                s2 = fmaf(v, v, s2);
            }
#pragma unroll
            for (int mask = 1; mask <= 8; mask <<= 1) s2 += __shfl_xor(s2, mask, 64);
            if (lr == 0) atomicAdd(&z_norm[m], s2);
        }
    }
}

// ---------------------------------------------------------------------------
// dist+argmin (MFMA split-f16): dot = z . c over D=256; d = (zn+cn) - 2*dot.
// Block 128 tokens x 128 codes; packed (dist_bits<<32|idx) atomicMin per row.
// ---------------------------------------------------------------------------
__global__ __launch_bounds__(256) void dist_mfma_kernel(
    const _Float16* __restrict__ zh, const _Float16* __restrict__ zl,
    const _Float16* __restrict__ ch, const _Float16* __restrict__ cl,
    const float* __restrict__ c_norm, const float* __restrict__ z_norm,
    u64* __restrict__ minpack) {
    __shared__ _Float16 Ah[8192], Al[8192], Bh[8192], Bl[8192];
    const int tid = threadIdx.x;
    const int w = tid >> 6, l = tid & 63;
    const int wy = (w >> 1) * 64, wx = (w & 1) * 64;
    const int m0 = blockIdx.y * 128, n0 = blockIdx.x * 128;
    const int lr = l & 15, quad = l >> 4;

    floatx4 acc[4][4] = {};

    for (int kt = 0; kt < DDIM; kt += 64) {
        __syncthreads();
#pragma unroll
        for (int j = 0; j < 4; ++j) {
            int s = j * 256 + tid;
            int row = s >> 3, c = s & 7, gc = c ^ (row & 7);
            size_t ga = (size_t)(m0 + row) * DDIM + kt + gc * 8;
            size_t gb = (size_t)(n0 + row) * DDIM + kt + gc * 8;
            gload16(zh + ga, Ah + s * 8);
            gload16(zl + ga, Al + s * 8);
            gload16(ch + gb, Bh + s * 8);
            gload16(cl + gb, Bl + s * 8);
        }
        __builtin_amdgcn_s_waitcnt(0);
        __syncthreads();
#pragma unroll
        for (int ks = 0; ks < 2; ++ks) {
            int c = ks * 4 + quad;
            half8 ah[4], al[4], bh[4], bl[4];
#pragma unroll
            for (int i = 0; i < 4; ++i) {
                int ar = wy + 16 * i + lr;
                int as = ar * 8 + (c ^ (ar & 7));
                ah[i] = *(const half8*)(Ah + as * 8);
                al[i] = *(const half8*)(Al + as * 8);
                int br = wx + 16 * i + lr;
                int bs = br * 8 + (c ^ (br & 7));
                bh[i] = *(const half8*)(Bh + bs * 8);
                bl[i] = *(const half8*)(Bl + bs * 8);
            }
#pragma unroll
            for (int i = 0; i < 4; ++i)
#pragma unroll
                for (int j = 0; j < 4; ++j) {
                    acc[i][j] = __builtin_amdgcn_mfma_f32_16x16x32_f16(ah[i], bh[j], acc[i][j], 0, 0, 0);
                    acc[i][j] = __builtin_amdgcn_mfma_f32_16x16x32_f16(ah[i], bl[j], acc[i][j], 0, 0, 0);
                    acc[i][j] = __builtin_amdgcn_mfma_f32_16x16x32_f16(al[i], bh[j], acc[i][j], 0, 0, 0);
                }
        }
    }

    float cnv[4];
#pragma unroll
    for (int j = 0; j < 4; ++j) cnv[j] = c_norm[n0 + wx + 16 * j + lr];
#pragma unroll
    for (int i = 0; i < 4; ++i) {
#pragma unroll
        for (int r = 0; r < 4; ++r) {
            int m = m0 + wy + 16 * i + quad * 4 + r;
            float zn = z_norm[m];
            u64 best = 0xFFFFFFFFFFFFFFFFull;
#pragma unroll
            for (int j = 0; j < 4; ++j) {
                float d = fmaf(-2.f, acc[i][j][r], zn + cnv[j]);
                int n = n0 + wx + 16 * j + lr;
                u64 p = (((u64)__float_as_uint(d)) << 32) | (unsigned)n;
                if (p < best) best = p;  // ties -> lower idx (matches np first-min)
            }
#pragma unroll
            for (int mask = 1; mask <= 8; mask <<= 1) {
                u64 q = __shfl_xor(best, mask, 64);
                if (q < best) best = q;
            }
            if (lr == 0) atomicMin(&minpack[m], best);
        }
    }
}

__global__ void unpack_kernel(const u64* __restrict__ minpack,
                              const float* __restrict__ prior, int* __restrict__ idx_i,
                              float* __restrict__ out_idx, int idx64,
                              float* __restrict__ accum) {
    int n = blockIdx.x * 256 + threadIdx.x;
    u64 p = minpack[n];
    int k = (int)(p & 0xffffffffull);
    float dist = __uint_as_float((unsigned)(p >> 32));
    idx_i[n] = k;
    if (idx64) ((long long*)out_idx)[n] = (long long)k;
    else out_idx[n] = (float)k;
    float sd = dist;
    float sp = prior[k];
#pragma unroll
    for (int m = 32; m; m >>= 1) {
        sd += __shfl_down(sd, m, 64);
        sp += __shfl_down(sp, m, 64);
    }
    __shared__ float ld[8];
    int lane = threadIdx.x & 63, wid = threadIdx.x >> 6;
    if (lane == 0) { ld[wid] = sd; ld[4 + wid] = sp; }
    __syncthreads();
    if (threadIdx.x == 0) {
        atomicAdd(&accum[0], ld[0] + ld[1] + ld[2] + ld[3]);
        atomicAdd(&accum[1], ld[4] + ld[5] + ld[6] + ld[7]);
    }
}

__global__ void finalize_kernel(const float* __restrict__ prior, const float* __restrict__ accum,
                                float* __restrict__ out_scalars) {
    __shared__ float wred[4];
    __shared__ float wred2[4];
    int tid = threadIdx.x;
    int lane = tid & 63, wid = tid >> 6;
    float mx = -3.4e38f;
    for (int i = tid; i < KCODE; i += 256) mx = fmaxf(mx, prior[i]);
#pragma unroll
    for (int m = 32; m; m >>= 1) mx = fmaxf(mx, __shfl_down(mx, m, 64));
    if (lane == 0) wred[wid] = mx;
    __syncthreads();
    mx = fmaxf(fmaxf(wred[0], wred[1]), fmaxf(wred[2], wred[3]));
    float se = 0.f;
    for (int i = tid; i < KCODE; i += 256) se += expf(prior[i] - mx);
#pragma unroll
    for (int m = 32; m; m >>= 1) se += __shfl_down(se, m, 64);
    if (lane == 0) wred2[wid] = se;
    __syncthreads();
    if (tid == 0) {
        float logZ = mx + logf(wred2[0] + wred2[1] + wred2[2] + wred2[3]);
        float rate = ((float)NTOK * logZ - accum[1]) * 1.4426950408889634f;
        float vq = 1.25f * accum[0] / ((float)NTOK * (float)DDIM);
        out_scalars[0] = rate;
        out_scalars[1] = vq;
    }
}

// postT = codebook @ post_w.T + post_b (f32 VALU; only 4.3 GF)
__global__ __launch_bounds__(256) void gemm_post_kernel(
    const float* __restrict__ codebook, const float* __restrict__ post_w,
    const float* __restrict__ post_b, float* __restrict__ postT) {
    __shared__ __align__(16) float As[16][132];
    __shared__ __align__(16) float Bs[16][132];
    const int tid = threadIdx.x;
    const int tx = tid & 15, ty = tid >> 4;
    const int k0 = blockIdx.x * 128;
    const int h0 = blockIdx.y * 128;

    float acc[8][8];
#pragma unroll
    for (int i = 0; i < 8; ++i)
#pragma unroll
        for (int j = 0; j < 8; ++j) acc[i][j] = 0.f;

    for (int dt = 0; dt < DDIM; dt += 16) {
#pragma unroll
        for (int j = 0; j < 2; ++j) {
            int s = tid + j * 256;
            int row = s >> 2, c4 = (s & 3) * 4;
            float4 v = *(const float4*)(codebook + (size_t)(k0 + row) * DDIM + dt + c4);
            As[c4 + 0][row] = v.x; As[c4 + 1][row] = v.y; As[c4 + 2][row] = v.z; As[c4 + 3][row] = v.w;
            float4 ww = *(const float4*)(post_w + (size_t)(h0 + row) * DDIM + dt + c4);
            Bs[c4 + 0][row] = ww.x; Bs[c4 + 1][row] = ww.y; Bs[c4 + 2][row] = ww.z; Bs[c4 + 3][row] = ww.w;
        }
        __syncthreads();
#pragma unroll
        for (int kk = 0; kk < 16; ++kk) {
            float4 a0 = *(const float4*)&As[kk][ty * 4];
            float4 a1 = *(const float4*)&As[kk][64 + ty * 4];
            float4 b0 = *(const float4*)&Bs[kk][tx * 4];
            float4 b1 = *(const float4*)&Bs[kk][64 + tx * 4];
            float a[8] = {a0.x, a0.y, a0.z, a0.w, a1.x, a1.y, a1.z, a1.w};
            float b[8] = {b0.x, b0.y, b0.z, b0.w, b1.x, b1.y, b1.z, b1.w};
#pragma unroll
            for (int i = 0; i < 8; ++i)
#pragma unroll
                for (int j = 0; j < 8; ++j) acc[i][j] = fmaf(a[i], b[j], acc[i][j]);
        }
        __syncthreads();
    }

    float4 pb0 = *(const float4*)(post_b + h0 + tx * 4);
    float4 pb1 = *(const float4*)(post_b + h0 + 64 + tx * 4);
#pragma unroll
    for (int i = 0; i < 8; ++i) {
        int rr = (i < 4) ? (ty * 4 + i) : (64 + ty * 4 + (i - 4));
        int k = k0 + rr;
        float4 v0 = make_float4(acc[i][0] + pb0.x, acc[i][1] + pb0.y, acc[i][2] + pb0.z, acc[i][3] + pb0.w);
        float4 v1 = make_float4(acc[i][4] + pb1.x, acc[i][5] + pb1.y, acc[i][6] + pb1.z, acc[i][7] + pb1.w);
        *(float4*)(postT + (size_t)k * HDIM + h0 + tx * 4) = v0;
        *(float4*)(postT + (size_t)k * HDIM + h0 + 64 + tx * 4) = v1;
    }
}

__global__ void gather_kernel(const float* __restrict__ postT, const int* __restrict__ idx_i,
                              float* __restrict__ out) {
    int n = blockIdx.x;
    int k = idx_i[n];
    const float4* src = (const float4*)(postT + (size_t)k * HDIM);
    float4* dst = (float4*)(out + (size_t)n * HDIM);
    int t = threadIdx.x;
    dst[t] = src[t];
    dst[t + 256] = src[t + 256];
}

extern "C" void kernel_launch(void* const* d_in, const int* in_sizes, int n_in,
                              void* d_out, int out_size, void* d_ws, size_t ws_size,
                              hipStream_t stream) {
    const float* embed = (const float*)d_in[0];
    const float* pre_w = (const float*)d_in[1];
    const float* pre_b = (const float*)d_in[2];
    const float* codebook = (const float*)d_in[3];
    const float* post_w = (const float*)d_in[4];
    const float* post_b = (const float*)d_in[5];
    const float* prior = (const float*)d_in[6];
    float* out = (float*)d_out;

    float* ws = (float*)d_ws;
    _Float16* z_hi = (_Float16*)(ws + WS_Z_HI);
    _Float16* z_lo = (_Float16*)(ws + WS_Z_LO);
    float* postT = ws + WS_POSTT;  // aliases z_hi/z_lo (dead after dist_mfma)
    _Float16* c_hi = (_Float16*)(ws + WS_C_HI);
    _Float16* c_lo = (_Float16*)(ws + WS_C_LO);
    _Float16* pw_hi = (_Float16*)(ws + WS_PW_HI);
    _Float16* pw_lo = (_Float16*)(ws + WS_PW_LO);
    float* z_norm = ws + WS_Z_NORM;
    float* c_norm = ws + WS_C_NORM;
    float* accum = ws + WS_ACCUM;
    u64* minpack = (u64*)(ws + WS_MINPACK);
    int* idx_i = (int*)(ws + WS_IDX);

    if (ws_size < (size_t)WS_END * 4) return;

    hipMemsetAsync(z_norm, 0, NTOK * 4, stream);
    hipMemsetAsync(accum, 0, 16, stream);
    hipMemsetAsync(minpack, 0xFF, NTOK * 8, stream);

    split_pw_kernel<<<512, 256, 0, stream>>>(pre_w, pw_hi, pw_lo);
    split_cb_kernel<<<KCODE, 64, 0, stream>>>(codebook, c_hi, c_lo, c_norm);
    pre_mfma_kernel<<<dim3(2, NTOK / 128), 256, 0, stream>>>(embed, pw_hi, pw_lo, pre_b,
                                                             z_hi, z_lo, z_norm);
    dist_mfma_kernel<<<dim3(KCODE / 128, NTOK / 128), 256, 0, stream>>>(
        z_hi, z_lo, c_hi, c_lo, c_norm, z_norm, minpack);

    int idx64 = (out_size == NTOK * HDIM + 2 * NTOK + 2) ? 1 : 0;
    unpack_kernel<<<NTOK / 256, 256, 0, stream>>>(minpack, prior, idx_i,
                                                  out + (size_t)NTOK * HDIM, idx64, accum);
    finalize_kernel<<<1, 256, 0, stream>>>(prior, accum, out + (out_size - 2));
    gemm_post_kernel<<<dim3(KCODE / 128, HDIM / 128), 256, 0, stream>>>(codebook, post_w, post_b, postT);
    gather_kernel<<<NTOK, 256, 0, stream>>>(postT, idx_i, out);
}